// Round 6
// baseline (458.609 us; speedup 1.0000x reference)
//
#include <hip/hip_runtime.h>
#include <cstdint>
#include <cstddef>

#define NF 128          // feature width (IN_F == HID_F == 128)
#define SCAN_B 256

typedef __attribute__((ext_vector_type(4))) float f32x4;
typedef __attribute__((ext_vector_type(8))) short bf16x8;

static __device__ inline float bf2f(short u) {
    union { unsigned u; float f; } v;
    v.u = ((unsigned)(unsigned short)u) << 16;
    return v.f;
}
static __device__ inline short f2bf(float f) {
    union { float f; unsigned u; } v; v.f = f;
    unsigned r = v.u + 0x7FFF + ((v.u >> 16) & 1);  // RNE
    return (short)(r >> 16);
}
static __device__ inline float u2f(unsigned u) {
    union { unsigned u; float f; } v; v.u = u; return v.f;
}
static __device__ inline unsigned f2u(float f) {
    union { float f; unsigned u; } v; v.f = f; return v.u;
}
static __device__ inline unsigned packbf(float lo, float hi) {
    unsigned ul = f2u(lo), uh = f2u(hi);
    ul = ul + 0x7FFF + ((ul >> 16) & 1);
    uh = uh + 0x7FFF + ((uh >> 16) & 1);
    return (ul >> 16) | (uh & 0xFFFF0000u);
}

// ---------------- degree / CSR build ----------------

static __global__ void k_count(const int* __restrict__ dst, int ne, int* __restrict__ counts) {
    int e = blockIdx.x * blockDim.x + threadIdx.x;
    if (e < ne) atomicAdd(&counts[dst[e]], 1);
}

static __global__ void k_dinv(const int* __restrict__ counts, int n, float* __restrict__ dinv) {
    int i = blockIdx.x * blockDim.x + threadIdx.x;
    if (i < n) {
        float d = (float)counts[i];
        d = fmaxf(d, 1.0f);
        dinv[i] = rsqrtf(d);
    }
}

static __global__ void k_scan1(const int* __restrict__ counts, int n,
                               int* __restrict__ row_off, int* __restrict__ bsum) {
    __shared__ int s[SCAN_B];
    int t = threadIdx.x;
    int base = blockIdx.x * SCAN_B;
    int v = (base + t < n) ? counts[base + t] : 0;
    s[t] = v;
    __syncthreads();
    for (int off = 1; off < SCAN_B; off <<= 1) {
        int x = 0;
        if (t >= off) x = s[t - off];
        __syncthreads();
        if (t >= off) s[t] += x;
        __syncthreads();
    }
    if (base + t < n) row_off[base + t] = s[t] - v;
    if (t == SCAN_B - 1) bsum[blockIdx.x] = s[t];
}

static __global__ void k_scan2(int* __restrict__ bsum, int nb) {
    __shared__ int s[512];
    int t = threadIdx.x;
    int v = (t < nb) ? bsum[t] : 0;
    s[t] = v;
    __syncthreads();
    for (int off = 1; off < 512; off <<= 1) {
        int x = 0;
        if (t >= off) x = s[t - off];
        __syncthreads();
        if (t >= off) s[t] += x;
        __syncthreads();
    }
    if (t < nb) bsum[t] = s[t] - v;
}

static __global__ void k_scan3(int* __restrict__ row_off, const int* __restrict__ bsum,
                               int n, int ne) {
    int i = blockIdx.x * SCAN_B + threadIdx.x;
    if (i < n) row_off[i] += bsum[blockIdx.x];
    if (i == 0) row_off[n] = ne;
}

static __global__ void k_copy_i32(const int* __restrict__ a, int* __restrict__ b, int n) {
    int i = blockIdx.x * blockDim.x + threadIdx.x;
    if (i < n) b[i] = a[i];
}

static __global__ void k_fill(const int* __restrict__ src, const int* __restrict__ dst, int ne,
                              int* __restrict__ cursor, int* __restrict__ csr) {
    int e = blockIdx.x * blockDim.x + threadIdx.x;
    if (e < ne) {
        int d = dst[e];
        int p = atomicAdd(&cursor[d], 1);
        csr[p] = src[e];
    }
}

// ---------------- fp32 -> bf16 convert ----------------

static __global__ __launch_bounds__(256) void k_cvt(const float* __restrict__ x,
                                                    short* __restrict__ y, int n8) {
    int i = blockIdx.x * blockDim.x + threadIdx.x;
    if (i < n8) {
        f32x4 a = *(const f32x4*)&x[(size_t)i * 8];
        f32x4 b = *(const f32x4*)&x[(size_t)i * 8 + 4];
        bf16x8 r;
        r[0] = f2bf(a[0]); r[1] = f2bf(a[1]); r[2] = f2bf(a[2]); r[3] = f2bf(a[3]);
        r[4] = f2bf(b[0]); r[5] = f2bf(b[1]); r[6] = f2bf(b[2]); r[7] = f2bf(b[3]);
        *(bf16x8*)&y[(size_t)i * 8] = r;
    }
}

// ---------------- Laplacian gather: one wave per node ----------------

static __global__ __launch_bounds__(256) void k_lap(
    const short* __restrict__ Xin, const short* __restrict__ Xo,
    const int* __restrict__ row_off, const int* __restrict__ csr,
    const float* __restrict__ dinv,
    float a, float b, float c,
    short* __restrict__ out, int n) {
    int node = blockIdx.x * 4 + (threadIdx.x >> 6);
    if (node >= n) return;
    int l = threadIdx.x & 63;
    const unsigned* Xu = (const unsigned*)Xin;
    int e0 = row_off[node], e1 = row_off[node + 1];

    float a0 = 0.f, a1 = 0.f, b0 = 0.f, b1 = 0.f;
    int e = e0;
    for (; e + 1 < e1; e += 2) {
        int s0 = csr[e], s1 = csr[e + 1];
        float d0 = dinv[s0], d1 = dinv[s1];
        unsigned v0 = Xu[(size_t)s0 * 64 + l];
        unsigned v1 = Xu[(size_t)s1 * 64 + l];
        a0 += u2f(v0 << 16) * d0;
        a1 += u2f(v0 & 0xFFFF0000u) * d0;
        b0 += u2f(v1 << 16) * d1;
        b1 += u2f(v1 & 0xFFFF0000u) * d1;
    }
    if (e < e1) {
        int s0 = csr[e];
        float d0 = dinv[s0];
        unsigned v0 = Xu[(size_t)s0 * 64 + l];
        a0 += u2f(v0 << 16) * d0;
        a1 += u2f(v0 & 0xFFFF0000u) * d0;
    }
    a0 += b0; a1 += b1;

    float di = dinv[node];
    unsigned xi = Xu[(size_t)node * 64 + l];
    float y0 = a * (a0 * di) + b * u2f(xi << 16);
    float y1 = a * (a1 * di) + b * u2f(xi & 0xFFFF0000u);
    if (Xo) {
        unsigned xo = ((const unsigned*)Xo)[(size_t)node * 64 + l];
        y0 += c * u2f(xo << 16);
        y1 += c * u2f(xo & 0xFFFF0000u);
    }
    ((unsigned*)out)[(size_t)node * 64 + l] = packbf(y0, y1);
}

// ---------------- conv GEMM: out[M][128] = concat(X0,X1,X2)[M][384] @ Wbf[128][384]^T ----
// BM=128, BN=128, BK=64, 6 K-steps. 4 waves 2x2, wave tile 64x64 (frag 4x4).
// 2-phase register-staged pipeline: issue loads(t+1) -> compute(t) -> barrier ->
// ds_write(t+1) -> barrier. LDS row stride 72 shorts (144 B): 16B-aligned, 2-way banks.
// mode 2: bn(relu(y+b))   mode 3: relu(y+b)+res.  Output bf16.

#define ALD 72

static __global__ __launch_bounds__(256, 3) void k_gemm_conv(
    const short* __restrict__ X0, const short* __restrict__ X1, const short* __restrict__ X2,
    const short* __restrict__ Wbf, const float* __restrict__ bias,
    const short* __restrict__ res,
    const float* __restrict__ bng, const float* __restrict__ bnb,
    const float* __restrict__ bnm, const float* __restrict__ bnv,
    int M, int mode, short* __restrict__ out) {
    __shared__ short As[128 * ALD];
    __shared__ short Bs[128 * ALD];

    const int t = threadIdx.x;
    const int m0 = blockIdx.x * 128;
    const int w  = t >> 6;
    const int wr = w >> 1;
    const int wc = w & 1;
    const int l  = t & 63;
    const int lr = l & 15;
    const int lk = l >> 4;

    const short* segs[3] = {X0, X1, X2};

    // staging task decomposition: 1024 chunks of 16B per tile, 4 per thread.
    // chunk c: row = c>>3 (0..127), slot = c&7 (16B units within 64-bf16 row).
    int srow[4], sslot[4];
#pragma unroll
    for (int i = 0; i < 4; ++i) {
        int c = i * 256 + t;
        srow[i] = c >> 3;
        sslot[i] = c & 7;
    }

    f32x4 acc[4][4];
#pragma unroll
    for (int i = 0; i < 4; ++i)
#pragma unroll
        for (int j = 0; j < 4; ++j) acc[i][j] = (f32x4){0.f, 0.f, 0.f, 0.f};

    bf16x8 ra[4], rb[4];

    auto load_regs = [&](int kt) {
        const short* Xp = segs[kt >> 7];
        const int klocal = kt & 127;
#pragma unroll
        for (int i = 0; i < 4; ++i) {
            int gm = m0 + srow[i];
            bf16x8 v = {0, 0, 0, 0, 0, 0, 0, 0};
            if (gm < M) v = *(const bf16x8*)&Xp[(size_t)gm * 128 + klocal + sslot[i] * 8];
            ra[i] = v;
            rb[i] = *(const bf16x8*)&Wbf[(size_t)srow[i] * 384 + kt + sslot[i] * 8];
        }
    };
    auto write_lds = [&]() {
#pragma unroll
        for (int i = 0; i < 4; ++i) {
            *(bf16x8*)&As[srow[i] * ALD + sslot[i] * 8] = ra[i];
            *(bf16x8*)&Bs[srow[i] * ALD + sslot[i] * 8] = rb[i];
        }
    };
    auto compute = [&]() {
#pragma unroll
        for (int kh = 0; kh < 2; ++kh) {
            bf16x8 af[4], bf[4];
#pragma unroll
            for (int fi = 0; fi < 4; ++fi)
                af[fi] = *(const bf16x8*)&As[(wr * 64 + fi * 16 + lr) * ALD + kh * 32 + lk * 8];
#pragma unroll
            for (int fj = 0; fj < 4; ++fj)
                bf[fj] = *(const bf16x8*)&Bs[(wc * 64 + fj * 16 + lr) * ALD + kh * 32 + lk * 8];
#pragma unroll
            for (int fi = 0; fi < 4; ++fi)
#pragma unroll
                for (int fj = 0; fj < 4; ++fj)
                    acc[fi][fj] = __builtin_amdgcn_mfma_f32_16x16x32_bf16(af[fi], bf[fj], acc[fi][fj], 0, 0, 0);
        }
    };

    load_regs(0);
    write_lds();
    __syncthreads();
#pragma unroll
    for (int tgt = 0; tgt < 6; ++tgt) {
        if (tgt < 5) load_regs((tgt + 1) * 64);   // issue next tile's global loads early
        compute();                                 // MFMA on current tile (hides load latency)
        __syncthreads();                           // all LDS reads of tile t done
        if (tgt < 5) {
            write_lds();                           // vmcnt wait lands here
            __syncthreads();                       // writes visible
        }
    }

    // epilogue: C row = lk*4+reg, col = lr
#pragma unroll
    for (int fi = 0; fi < 4; ++fi) {
#pragma unroll
        for (int reg = 0; reg < 4; ++reg) {
            int gm = m0 + wr * 64 + fi * 16 + lk * 4 + reg;
            if (gm >= M) continue;
#pragma unroll
            for (int fj = 0; fj < 4; ++fj) {
                int gn = wc * 64 + fj * 16 + lr;
                float y = acc[fi][fj][reg] + bias[gn];
                y = fmaxf(y, 0.f);
                if (mode == 2) {
                    float sc = rsqrtf(bnv[gn] + 1e-5f) * bng[gn];
                    y = (y - bnm[gn]) * sc + bnb[gn];
                } else {
                    y += bf2f(res[(size_t)gm * 128 + gn]);
                }
                out[(size_t)gm * 128 + gn] = f2bf(y);
            }
        }
    }
}

// ---------------- fused MLP: out[M][64] = relu(x@Wm1^T+bm1) @ Wm2^T + bm2 ----------------

#define LDP 40

static __global__ __launch_bounds__(256) void k_mlp(
    const short* __restrict__ X, const short* __restrict__ Wm1bf, const float* __restrict__ bm1,
    const short* __restrict__ Wm2bf, const float* __restrict__ bm2,
    int M, float* __restrict__ out) {
    __shared__ short As[64 * LDP];       // phase1 A tile / phase2 B tile
    __shared__ short Bs[128 * LDP];      // phase1 Wm1 tile
    __shared__ short hs[64 * 136];       // h, padded stride 136

    const int t = threadIdx.x;
    const int m0 = blockIdx.x * 64;
    const int w  = t >> 6;
    const int wr = w >> 1;
    const int wc = w & 1;
    const int l  = t & 63;
    const int lr = l & 15;
    const int lk = l >> 4;

    f32x4 acc1[2][4];
#pragma unroll
    for (int i = 0; i < 2; ++i)
#pragma unroll
        for (int j = 0; j < 4; ++j) acc1[i][j] = (f32x4){0.f, 0.f, 0.f, 0.f};

    for (int kt = 0; kt < 128; kt += 32) {
        {
            int row = t >> 2;
            int slot = t & 3;
            int gm = m0 + row;
            bf16x8 v = {0, 0, 0, 0, 0, 0, 0, 0};
            if (gm < M) v = *(const bf16x8*)&X[(size_t)gm * 128 + kt + slot * 8];
            *(bf16x8*)&As[row * LDP + slot * 8] = v;
        }
#pragma unroll
        for (int it = 0; it < 2; ++it) {
            int idx = it * 256 + t;
            int row = idx >> 2;
            int slot = idx & 3;
            bf16x8 v = *(const bf16x8*)&Wm1bf[(size_t)row * 128 + kt + slot * 8];
            *(bf16x8*)&Bs[row * LDP + slot * 8] = v;
        }
        __syncthreads();

        bf16x8 af[2], bfr[4];
#pragma unroll
        for (int fi = 0; fi < 2; ++fi)
            af[fi] = *(const bf16x8*)&As[(wr * 32 + fi * 16 + lr) * LDP + lk * 8];
#pragma unroll
        for (int fj = 0; fj < 4; ++fj)
            bfr[fj] = *(const bf16x8*)&Bs[(wc * 64 + fj * 16 + lr) * LDP + lk * 8];
#pragma unroll
        for (int fi = 0; fi < 2; ++fi)
#pragma unroll
            for (int fj = 0; fj < 4; ++fj)
                acc1[fi][fj] = __builtin_amdgcn_mfma_f32_16x16x32_bf16(af[fi], bfr[fj], acc1[fi][fj], 0, 0, 0);
        __syncthreads();
    }

#pragma unroll
    for (int fi = 0; fi < 2; ++fi) {
#pragma unroll
        for (int reg = 0; reg < 4; ++reg) {
            int rloc = wr * 32 + fi * 16 + lk * 4 + reg;
#pragma unroll
            for (int fj = 0; fj < 4; ++fj) {
                int col = wc * 64 + fj * 16 + lr;
                float y = acc1[fi][fj][reg] + bm1[col];
                hs[rloc * 136 + col] = f2bf(fmaxf(y, 0.f));
            }
        }
    }
    __syncthreads();

    f32x4 acc2[2][2];
#pragma unroll
    for (int i = 0; i < 2; ++i)
#pragma unroll
        for (int j = 0; j < 2; ++j) acc2[i][j] = (f32x4){0.f, 0.f, 0.f, 0.f};

    for (int kt = 0; kt < 128; kt += 32) {
        {
            int row = t >> 2;
            int slot = t & 3;
            bf16x8 v = *(const bf16x8*)&Wm2bf[(size_t)row * 128 + kt + slot * 8];
            *(bf16x8*)&As[row * LDP + slot * 8] = v;
        }
        __syncthreads();

        bf16x8 af[2], bfr[2];
#pragma unroll
        for (int fi = 0; fi < 2; ++fi)
            af[fi] = *(const bf16x8*)&hs[(wr * 32 + fi * 16 + lr) * 136 + kt + lk * 8];
#pragma unroll
        for (int fj = 0; fj < 2; ++fj)
            bfr[fj] = *(const bf16x8*)&As[(wc * 32 + fj * 16 + lr) * LDP + lk * 8];
#pragma unroll
        for (int fi = 0; fi < 2; ++fi)
#pragma unroll
            for (int fj = 0; fj < 2; ++fj)
                acc2[fi][fj] = __builtin_amdgcn_mfma_f32_16x16x32_bf16(af[fi], bfr[fj], acc2[fi][fj], 0, 0, 0);
        __syncthreads();
    }

#pragma unroll
    for (int fi = 0; fi < 2; ++fi) {
#pragma unroll
        for (int reg = 0; reg < 4; ++reg) {
            int gm = m0 + wr * 32 + fi * 16 + lk * 4 + reg;
            if (gm >= M) continue;
#pragma unroll
            for (int fj = 0; fj < 2; ++fj) {
                int gn = wc * 32 + fj * 16 + lr;
                out[(size_t)gm * 64 + gn] = acc2[fi][fj][reg] + bm2[gn];
            }
        }
    }
}

// ---------------- launch ----------------

extern "C" void kernel_launch(void* const* d_in, const int* in_sizes, int n_in,
                              void* d_out, int out_size, void* d_ws, size_t ws_size,
                              hipStream_t stream) {
    const float* features = (const float*)d_in[0];
    const int*   esrc     = (const int*)d_in[1];
    const int*   edst     = (const int*)d_in[2];
    const float* W1   = (const float*)d_in[3];
    const float* b1   = (const float*)d_in[4];
    const float* bng  = (const float*)d_in[5];
    const float* bnb  = (const float*)d_in[6];
    const float* bnm  = (const float*)d_in[7];
    const float* bnv  = (const float*)d_in[8];
    const float* W3   = (const float*)d_in[9];
    const float* b3   = (const float*)d_in[10];
    const float* Wm1  = (const float*)d_in[11];
    const float* bm1  = (const float*)d_in[12];
    const float* Wm2  = (const float*)d_in[13];
    const float* bm2  = (const float*)d_in[14];
    float* out = (float*)d_out;

    const int n  = in_sizes[0] / NF;     // 100000
    const int ne = in_sizes[1];          // 600000

    uint8_t* w = (uint8_t*)d_ws;
    size_t off = 0;
    auto alloc = [&](size_t bytes) -> void* {
        void* p = w + off;
        off = (off + bytes + 255) & ~(size_t)255;
        return p;
    };
    float* dinv   = (float*)alloc((size_t)n * 4);
    int* counts   = (int*)alloc((size_t)n * 4);
    int* row_off  = (int*)alloc(((size_t)n + 1) * 4);
    int* cursor   = (int*)alloc((size_t)n * 4);
    int* csr      = (int*)alloc((size_t)ne * 4);
    int* bsum     = (int*)alloc(4096);
    short* fbf    = (short*)alloc((size_t)n * NF * 2);
    short* bufB   = (short*)alloc((size_t)n * NF * 2);
    short* bufC   = (short*)alloc((size_t)n * NF * 2);
    short* bufD   = (short*)alloc((size_t)n * NF * 2);
    short* bufE   = (short*)alloc((size_t)n * NF * 2);
    short* W1bf   = (short*)alloc((size_t)128 * 384 * 2);
    short* W3bf   = (short*)alloc((size_t)128 * 384 * 2);
    short* Wm1bf  = (short*)alloc((size_t)128 * 128 * 2);
    short* Wm2bf  = (short*)alloc((size_t)64 * 128 * 2);
    (void)ws_size;

    const int TB = 256;
    const int nbE = (ne + TB - 1) / TB;
    const int nbN = (n + TB - 1) / TB;

    hipMemsetAsync(counts, 0, (size_t)n * 4, stream);
    k_count<<<nbE, TB, 0, stream>>>(edst, ne, counts);
    k_dinv<<<nbN, TB, 0, stream>>>(counts, n, dinv);
    k_scan1<<<nbN, SCAN_B, 0, stream>>>(counts, n, row_off, bsum);
    k_scan2<<<1, 512, 0, stream>>>(bsum, nbN);
    k_scan3<<<nbN, SCAN_B, 0, stream>>>(row_off, bsum, n, ne);
    k_copy_i32<<<nbN, TB, 0, stream>>>(row_off, cursor, n);
    k_fill<<<nbE, TB, 0, stream>>>(esrc, edst, ne, cursor, csr);

    {
        int n8 = n * NF / 8;
        k_cvt<<<(n8 + 255) / 256, 256, 0, stream>>>(features, fbf, n8);
        k_cvt<<<(6144 + 255) / 256, 256, 0, stream>>>(W1, W1bf, 6144);
        k_cvt<<<(6144 + 255) / 256, 256, 0, stream>>>(W3, W3bf, 6144);
        k_cvt<<<(2048 + 255) / 256, 256, 0, stream>>>(Wm1, Wm1bf, 2048);
        k_cvt<<<(1024 + 255) / 256, 256, 0, stream>>>(Wm2, Wm2bf, 1024);
    }

    const int gm128 = (n + 127) / 128;
    const int gm64  = (n + 63) / 64;
    const int nbL   = (n + 3) / 4;   // lap: 4 nodes per 256-thread block

    // ---- conv1 ----
    k_lap<<<nbL, 256, 0, stream>>>(fbf, nullptr, row_off, csr, dinv, 1.f, -1.f, 0.f, bufB, n);
    k_lap<<<nbL, 256, 0, stream>>>(bufB, fbf, row_off, csr, dinv, 2.f, -2.f, -1.f, bufC, n);
    k_gemm_conv<<<gm128, 256, 0, stream>>>(fbf, bufB, bufC, W1bf, b1,
                                           nullptr, bng, bnb, bnm, bnv, n, 2, bufD);

    // ---- conv2 ----
    k_lap<<<nbL, 256, 0, stream>>>(bufD, nullptr, row_off, csr, dinv, 1.f, -1.f, 0.f, bufB, n);
    k_lap<<<nbL, 256, 0, stream>>>(bufB, bufD, row_off, csr, dinv, 2.f, -2.f, -1.f, bufC, n);
    k_gemm_conv<<<gm128, 256, 0, stream>>>(bufD, bufB, bufC, W3bf, b3,
                                           bufD, nullptr, nullptr, nullptr, nullptr, n, 3, bufE);

    // ---- fused MLP ----
    k_mlp<<<gm64, 256, 0, stream>>>(bufE, Wm1bf, bm1, Wm2bf, bm2, n, out);
}

// Round 7
// 428.355 us; speedup vs baseline: 1.0706x; 1.0706x over previous
//
#include <hip/hip_runtime.h>
#include <cstdint>
#include <cstddef>

#define NF 128          // feature width (IN_F == HID_F == 128)
#define SCAN_B 256

typedef __attribute__((ext_vector_type(4))) float f32x4;
typedef __attribute__((ext_vector_type(8))) short bf16x8;

static __device__ inline float bf2f(short u) {
    union { unsigned u; float f; } v;
    v.u = ((unsigned)(unsigned short)u) << 16;
    return v.f;
}
static __device__ inline short f2bf(float f) {
    union { float f; unsigned u; } v; v.f = f;
    unsigned r = v.u + 0x7FFF + ((v.u >> 16) & 1);  // RNE
    return (short)(r >> 16);
}
static __device__ inline float u2f(unsigned u) {
    union { unsigned u; float f; } v; v.u = u; return v.f;
}
static __device__ inline unsigned f2u(float f) {
    union { float f; unsigned u; } v; v.f = f; return v.u;
}
static __device__ inline unsigned packbf(float lo, float hi) {
    unsigned ul = f2u(lo), uh = f2u(hi);
    ul = ul + 0x7FFF + ((ul >> 16) & 1);
    uh = uh + 0x7FFF + ((uh >> 16) & 1);
    return (ul >> 16) | (uh & 0xFFFF0000u);
}

// ---------------- degree / CSR build ----------------

static __global__ void k_count(const int* __restrict__ dst, int ne, int* __restrict__ counts) {
    int e = blockIdx.x * blockDim.x + threadIdx.x;
    if (e < ne) atomicAdd(&counts[dst[e]], 1);
}

static __global__ void k_dinv(const int* __restrict__ counts, int n, float* __restrict__ dinv) {
    int i = blockIdx.x * blockDim.x + threadIdx.x;
    if (i < n) {
        float d = (float)counts[i];
        d = fmaxf(d, 1.0f);
        dinv[i] = rsqrtf(d);
    }
}

static __global__ void k_scan1(const int* __restrict__ counts, int n,
                               int* __restrict__ row_off, int* __restrict__ bsum) {
    __shared__ int s[SCAN_B];
    int t = threadIdx.x;
    int base = blockIdx.x * SCAN_B;
    int v = (base + t < n) ? counts[base + t] : 0;
    s[t] = v;
    __syncthreads();
    for (int off = 1; off < SCAN_B; off <<= 1) {
        int x = 0;
        if (t >= off) x = s[t - off];
        __syncthreads();
        if (t >= off) s[t] += x;
        __syncthreads();
    }
    if (base + t < n) row_off[base + t] = s[t] - v;
    if (t == SCAN_B - 1) bsum[blockIdx.x] = s[t];
}

static __global__ void k_scan2(int* __restrict__ bsum, int nb) {
    __shared__ int s[512];
    int t = threadIdx.x;
    int v = (t < nb) ? bsum[t] : 0;
    s[t] = v;
    __syncthreads();
    for (int off = 1; off < 512; off <<= 1) {
        int x = 0;
        if (t >= off) x = s[t - off];
        __syncthreads();
        if (t >= off) s[t] += x;
        __syncthreads();
    }
    if (t < nb) bsum[t] = s[t] - v;
}

static __global__ void k_scan3(int* __restrict__ row_off, const int* __restrict__ bsum,
                               int n, int ne, int* __restrict__ cursor) {
    int i = blockIdx.x * SCAN_B + threadIdx.x;
    if (i < n) {
        int v = row_off[i] + bsum[blockIdx.x];
        row_off[i] = v;
        cursor[i] = v;
    }
    if (i == 0) row_off[n] = ne;
}

static __global__ void k_fill(const int* __restrict__ src, const int* __restrict__ dst, int ne,
                              int* __restrict__ cursor, int* __restrict__ csr) {
    int e = blockIdx.x * blockDim.x + threadIdx.x;
    if (e < ne) {
        int d = dst[e];
        int p = atomicAdd(&cursor[d], 1);
        csr[p] = src[e];
    }
}

// ---------------- fp32 -> bf16 convert ----------------

static __global__ __launch_bounds__(256) void k_cvt(const float* __restrict__ x,
                                                    short* __restrict__ y, int n8) {
    int i = blockIdx.x * blockDim.x + threadIdx.x;
    if (i < n8) {
        f32x4 a = *(const f32x4*)&x[(size_t)i * 8];
        f32x4 b = *(const f32x4*)&x[(size_t)i * 8 + 4];
        bf16x8 r;
        r[0] = f2bf(a[0]); r[1] = f2bf(a[1]); r[2] = f2bf(a[2]); r[3] = f2bf(a[3]);
        r[4] = f2bf(b[0]); r[5] = f2bf(b[1]); r[6] = f2bf(b[2]); r[7] = f2bf(b[3]);
        *(bf16x8*)&y[(size_t)i * 8] = r;
    }
}

// merged weight convert: 4 segments [W1:6144][W3:6144][Wm1:2048][Wm2:1024] x8 chunks
static __global__ __launch_bounds__(256) void k_cvtw(
    const float* __restrict__ w1, const float* __restrict__ w3,
    const float* __restrict__ wm1, const float* __restrict__ wm2,
    short* __restrict__ o1, short* __restrict__ o3,
    short* __restrict__ om1, short* __restrict__ om2) {
    int i = blockIdx.x * blockDim.x + threadIdx.x;   // 0..15359
    const float* x; short* y; int off;
    if (i < 6144)       { x = w1;  y = o1;  off = i; }
    else if (i < 12288) { x = w3;  y = o3;  off = i - 6144; }
    else if (i < 14336) { x = wm1; y = om1; off = i - 12288; }
    else                { x = wm2; y = om2; off = i - 14336; }
    f32x4 a = *(const f32x4*)&x[(size_t)off * 8];
    f32x4 b = *(const f32x4*)&x[(size_t)off * 8 + 4];
    bf16x8 r;
    r[0] = f2bf(a[0]); r[1] = f2bf(a[1]); r[2] = f2bf(a[2]); r[3] = f2bf(a[3]);
    r[4] = f2bf(b[0]); r[5] = f2bf(b[1]); r[6] = f2bf(b[2]); r[7] = f2bf(b[3]);
    *(bf16x8*)&y[(size_t)off * 8] = r;
}

// ---------------- Laplacian gather: one wave per node ----------------

static __global__ __launch_bounds__(256) void k_lap(
    const short* __restrict__ Xin, const short* __restrict__ Xo,
    const int* __restrict__ row_off, const int* __restrict__ csr,
    const float* __restrict__ dinv,
    float a, float b, float c,
    short* __restrict__ out, int n) {
    int node = blockIdx.x * 4 + (threadIdx.x >> 6);
    if (node >= n) return;
    int l = threadIdx.x & 63;
    const unsigned* Xu = (const unsigned*)Xin;
    int e0 = row_off[node], e1 = row_off[node + 1];

    float a0 = 0.f, a1 = 0.f, b0 = 0.f, b1 = 0.f;
    int e = e0;
    for (; e + 1 < e1; e += 2) {
        int s0 = csr[e], s1 = csr[e + 1];
        float d0 = dinv[s0], d1 = dinv[s1];
        unsigned v0 = Xu[(size_t)s0 * 64 + l];
        unsigned v1 = Xu[(size_t)s1 * 64 + l];
        a0 += u2f(v0 << 16) * d0;
        a1 += u2f(v0 & 0xFFFF0000u) * d0;
        b0 += u2f(v1 << 16) * d1;
        b1 += u2f(v1 & 0xFFFF0000u) * d1;
    }
    if (e < e1) {
        int s0 = csr[e];
        float d0 = dinv[s0];
        unsigned v0 = Xu[(size_t)s0 * 64 + l];
        a0 += u2f(v0 << 16) * d0;
        a1 += u2f(v0 & 0xFFFF0000u) * d0;
    }
    a0 += b0; a1 += b1;

    float di = dinv[node];
    unsigned xi = Xu[(size_t)node * 64 + l];
    float y0 = a * (a0 * di) + b * u2f(xi << 16);
    float y1 = a * (a1 * di) + b * u2f(xi & 0xFFFF0000u);
    if (Xo) {
        unsigned xo = ((const unsigned*)Xo)[(size_t)node * 64 + l];
        y0 += c * u2f(xo << 16);
        y1 += c * u2f(xo & 0xFFFF0000u);
    }
    ((unsigned*)out)[(size_t)node * 64 + l] = packbf(y0, y1);
}

// ---------------- conv GEMM: out[M][128] = concat(X0,X1,X2)[M][384] @ Wbf[128][384]^T ----
// R4 geometry (BM=128, BN=64, grid.y=2, BK=32, 4 waves 2x2, frag 4x2) +
// double-buffered LDS + register prefetch, ONE barrier per K-step:
//   load_regs(t+1) -> compute(buf[t&1]) -> write_lds(buf[(t+1)&1]) -> barrier.
// The barrier sits between last read of a buffer and its next overwrite (safe).
// mode 2: bn(relu(y+b))   mode 3: relu(y+b)+res.  Output bf16.

#define LDP 40

static __global__ __launch_bounds__(256) void k_gemm_conv(
    const short* __restrict__ X0, const short* __restrict__ X1, const short* __restrict__ X2,
    const short* __restrict__ Wbf, const float* __restrict__ bias,
    const short* __restrict__ res,
    const float* __restrict__ bng, const float* __restrict__ bnb,
    const float* __restrict__ bnm, const float* __restrict__ bnv,
    int M, int mode, short* __restrict__ out) {
    __shared__ short As[2][128 * LDP];
    __shared__ short Bs[2][64 * LDP];

    const int t = threadIdx.x;
    const int m0 = blockIdx.x * 128;
    const int n0 = blockIdx.y * 64;
    const int w  = t >> 6;
    const int wr = w >> 1;
    const int wc = w & 1;
    const int l  = t & 63;
    const int lr = l & 15;
    const int lk = l >> 4;

    const short* segs[3] = {X0, X1, X2};

    // A staging: 512 chunks (row 0..127, slot 0..3), 2/thread. B: 256 chunks, 1/thread.
    const int ar0 = t >> 2, as0 = t & 3;               // chunk t
    const int ar1 = (256 + t) >> 2, as1 = t & 3;       // chunk 256+t
    const int br  = t >> 2, bs = t & 3;

    f32x4 acc[4][2];
#pragma unroll
    for (int i = 0; i < 4; ++i)
#pragma unroll
        for (int j = 0; j < 2; ++j) acc[i][j] = (f32x4){0.f, 0.f, 0.f, 0.f};

    bf16x8 ra0, ra1, rb;

    auto load_regs = [&](int kt) {
        const short* Xp = segs[kt >> 7];
        const int klocal = kt & 127;
        int gm0 = m0 + ar0, gm1 = m0 + ar1;
        bf16x8 z = {0, 0, 0, 0, 0, 0, 0, 0};
        ra0 = (gm0 < M) ? *(const bf16x8*)&Xp[(size_t)gm0 * 128 + klocal + as0 * 8] : z;
        ra1 = (gm1 < M) ? *(const bf16x8*)&Xp[(size_t)gm1 * 128 + klocal + as1 * 8] : z;
        rb  = *(const bf16x8*)&Wbf[(size_t)(n0 + br) * 384 + kt + bs * 8];
    };
    auto write_lds = [&](int buf) {
        *(bf16x8*)&As[buf][ar0 * LDP + as0 * 8] = ra0;
        *(bf16x8*)&As[buf][ar1 * LDP + as1 * 8] = ra1;
        *(bf16x8*)&Bs[buf][br * LDP + bs * 8] = rb;
    };
    auto compute = [&](int buf) {
        bf16x8 af[4], bfr[2];
#pragma unroll
        for (int fi = 0; fi < 4; ++fi)
            af[fi] = *(const bf16x8*)&As[buf][(wr * 64 + fi * 16 + lr) * LDP + lk * 8];
#pragma unroll
        for (int fj = 0; fj < 2; ++fj)
            bfr[fj] = *(const bf16x8*)&Bs[buf][(wc * 32 + fj * 16 + lr) * LDP + lk * 8];
#pragma unroll
        for (int fi = 0; fi < 4; ++fi)
#pragma unroll
            for (int fj = 0; fj < 2; ++fj)
                acc[fi][fj] = __builtin_amdgcn_mfma_f32_16x16x32_bf16(af[fi], bfr[fj], acc[fi][fj], 0, 0, 0);
    };

    load_regs(0);
    write_lds(0);
    __syncthreads();
#pragma unroll
    for (int tgt = 0; tgt < 12; ++tgt) {
        if (tgt < 11) load_regs((tgt + 1) * 32);   // issue next tile loads (latency hidden)
        compute(tgt & 1);
        if (tgt < 11) {
            write_lds((tgt + 1) & 1);              // other buffer: no race with readers
            __syncthreads();                       // writes visible before next read
        }
    }

    // epilogue: C row = lk*4+reg, col = lr
#pragma unroll
    for (int fi = 0; fi < 4; ++fi) {
#pragma unroll
        for (int reg = 0; reg < 4; ++reg) {
            int gm = m0 + wr * 64 + fi * 16 + lk * 4 + reg;
            if (gm >= M) continue;
#pragma unroll
            for (int fj = 0; fj < 2; ++fj) {
                int gn = n0 + wc * 32 + fj * 16 + lr;
                float y = acc[fi][fj][reg] + bias[gn];
                y = fmaxf(y, 0.f);
                if (mode == 2) {
                    float sc = rsqrtf(bnv[gn] + 1e-5f) * bng[gn];
                    y = (y - bnm[gn]) * sc + bnb[gn];
                } else {
                    y += bf2f(res[(size_t)gm * 128 + gn]);
                }
                out[(size_t)gm * 128 + gn] = f2bf(y);
            }
        }
    }
}

// ---------------- fused MLP: out[M][64] = relu(x@Wm1^T+bm1) @ Wm2^T + bm2 ----------------

static __global__ __launch_bounds__(256) void k_mlp(
    const short* __restrict__ X, const short* __restrict__ Wm1bf, const float* __restrict__ bm1,
    const short* __restrict__ Wm2bf, const float* __restrict__ bm2,
    int M, float* __restrict__ out) {
    __shared__ short As[64 * LDP];       // phase1 A tile / phase2 B tile
    __shared__ short Bs[128 * LDP];      // phase1 Wm1 tile
    __shared__ short hs[64 * 136];       // h, padded stride 136

    const int t = threadIdx.x;
    const int m0 = blockIdx.x * 64;
    const int w  = t >> 6;
    const int wr = w >> 1;
    const int wc = w & 1;
    const int l  = t & 63;
    const int lr = l & 15;
    const int lk = l >> 4;

    f32x4 acc1[2][4];
#pragma unroll
    for (int i = 0; i < 2; ++i)
#pragma unroll
        for (int j = 0; j < 4; ++j) acc1[i][j] = (f32x4){0.f, 0.f, 0.f, 0.f};

    for (int kt = 0; kt < 128; kt += 32) {
        {
            int row = t >> 2;
            int slot = t & 3;
            int gm = m0 + row;
            bf16x8 v = {0, 0, 0, 0, 0, 0, 0, 0};
            if (gm < M) v = *(const bf16x8*)&X[(size_t)gm * 128 + kt + slot * 8];
            *(bf16x8*)&As[row * LDP + slot * 8] = v;
        }
#pragma unroll
        for (int it = 0; it < 2; ++it) {
            int idx = it * 256 + t;
            int row = idx >> 2;
            int slot = idx & 3;
            bf16x8 v = *(const bf16x8*)&Wm1bf[(size_t)row * 128 + kt + slot * 8];
            *(bf16x8*)&Bs[row * LDP + slot * 8] = v;
        }
        __syncthreads();

        bf16x8 af[2], bfr[4];
#pragma unroll
        for (int fi = 0; fi < 2; ++fi)
            af[fi] = *(const bf16x8*)&As[(wr * 32 + fi * 16 + lr) * LDP + lk * 8];
#pragma unroll
        for (int fj = 0; fj < 4; ++fj)
            bfr[fj] = *(const bf16x8*)&Bs[(wc * 64 + fj * 16 + lr) * LDP + lk * 8];
#pragma unroll
        for (int fi = 0; fi < 2; ++fi)
#pragma unroll
            for (int fj = 0; fj < 4; ++fj)
                acc1[fi][fj] = __builtin_amdgcn_mfma_f32_16x16x32_bf16(af[fi], bfr[fj], acc1[fi][fj], 0, 0, 0);
        __syncthreads();
    }

#pragma unroll
    for (int fi = 0; fi < 2; ++fi) {
#pragma unroll
        for (int reg = 0; reg < 4; ++reg) {
            int rloc = wr * 32 + fi * 16 + lk * 4 + reg;
#pragma unroll
            for (int fj = 0; fj < 4; ++fj) {
                int col = wc * 64 + fj * 16 + lr;
                float y = acc1[fi][fj][reg] + bm1[col];
                hs[rloc * 136 + col] = f2bf(fmaxf(y, 0.f));
            }
        }
    }
    __syncthreads();

    f32x4 acc2[2][2];
#pragma unroll
    for (int i = 0; i < 2; ++i)
#pragma unroll
        for (int j = 0; j < 2; ++j) acc2[i][j] = (f32x4){0.f, 0.f, 0.f, 0.f};

    for (int kt = 0; kt < 128; kt += 32) {
        {
            int row = t >> 2;
            int slot = t & 3;
            bf16x8 v = *(const bf16x8*)&Wm2bf[(size_t)row * 128 + kt + slot * 8];
            *(bf16x8*)&As[row * LDP + slot * 8] = v;
        }
        __syncthreads();

        bf16x8 af[2], bfr[2];
#pragma unroll
        for (int fi = 0; fi < 2; ++fi)
            af[fi] = *(const bf16x8*)&hs[(wr * 32 + fi * 16 + lr) * 136 + kt + lk * 8];
#pragma unroll
        for (int fj = 0; fj < 2; ++fj)
            bfr[fj] = *(const bf16x8*)&As[(wc * 32 + fj * 16 + lr) * LDP + lk * 8];
#pragma unroll
        for (int fi = 0; fi < 2; ++fi)
#pragma unroll
            for (int fj = 0; fj < 2; ++fj)
                acc2[fi][fj] = __builtin_amdgcn_mfma_f32_16x16x32_bf16(af[fi], bfr[fj], acc2[fi][fj], 0, 0, 0);
        __syncthreads();
    }

#pragma unroll
    for (int fi = 0; fi < 2; ++fi) {
#pragma unroll
        for (int reg = 0; reg < 4; ++reg) {
            int gm = m0 + wr * 32 + fi * 16 + lk * 4 + reg;
            if (gm >= M) continue;
#pragma unroll
            for (int fj = 0; fj < 2; ++fj) {
                int gn = wc * 32 + fj * 16 + lr;
                out[(size_t)gm * 64 + gn] = acc2[fi][fj][reg] + bm2[gn];
            }
        }
    }
}

// ---------------- launch ----------------

extern "C" void kernel_launch(void* const* d_in, const int* in_sizes, int n_in,
                              void* d_out, int out_size, void* d_ws, size_t ws_size,
                              hipStream_t stream) {
    const float* features = (const float*)d_in[0];
    const int*   esrc     = (const int*)d_in[1];
    const int*   edst     = (const int*)d_in[2];
    const float* W1   = (const float*)d_in[3];
    const float* b1   = (const float*)d_in[4];
    const float* bng  = (const float*)d_in[5];
    const float* bnb  = (const float*)d_in[6];
    const float* bnm  = (const float*)d_in[7];
    const float* bnv  = (const float*)d_in[8];
    const float* W3   = (const float*)d_in[9];
    const float* b3   = (const float*)d_in[10];
    const float* Wm1  = (const float*)d_in[11];
    const float* bm1  = (const float*)d_in[12];
    const float* Wm2  = (const float*)d_in[13];
    const float* bm2  = (const float*)d_in[14];
    float* out = (float*)d_out;

    const int n  = in_sizes[0] / NF;     // 100000
    const int ne = in_sizes[1];          // 600000

    uint8_t* w = (uint8_t*)d_ws;
    size_t off = 0;
    auto alloc = [&](size_t bytes) -> void* {
        void* p = w + off;
        off = (off + bytes + 255) & ~(size_t)255;
        return p;
    };
    float* dinv   = (float*)alloc((size_t)n * 4);
    int* counts   = (int*)alloc((size_t)n * 4);
    int* row_off  = (int*)alloc(((size_t)n + 1) * 4);
    int* cursor   = (int*)alloc((size_t)n * 4);
    int* csr      = (int*)alloc((size_t)ne * 4);
    int* bsum     = (int*)alloc(4096);
    short* fbf    = (short*)alloc((size_t)n * NF * 2);
    short* bufB   = (short*)alloc((size_t)n * NF * 2);
    short* bufC   = (short*)alloc((size_t)n * NF * 2);
    short* bufD   = (short*)alloc((size_t)n * NF * 2);
    short* bufE   = (short*)alloc((size_t)n * NF * 2);
    short* W1bf   = (short*)alloc((size_t)128 * 384 * 2);
    short* W3bf   = (short*)alloc((size_t)128 * 384 * 2);
    short* Wm1bf  = (short*)alloc((size_t)128 * 128 * 2);
    short* Wm2bf  = (short*)alloc((size_t)64 * 128 * 2);
    (void)ws_size;

    const int TB = 256;
    const int nbE = (ne + TB - 1) / TB;
    const int nbN = (n + TB - 1) / TB;

    hipMemsetAsync(counts, 0, (size_t)n * 4, stream);
    k_count<<<nbE, TB, 0, stream>>>(edst, ne, counts);
    k_dinv<<<nbN, TB, 0, stream>>>(counts, n, dinv);
    k_scan1<<<nbN, SCAN_B, 0, stream>>>(counts, n, row_off, bsum);
    k_scan2<<<1, 512, 0, stream>>>(bsum, nbN);
    k_scan3<<<nbN, SCAN_B, 0, stream>>>(row_off, bsum, n, ne, cursor);
    k_fill<<<nbE, TB, 0, stream>>>(esrc, edst, ne, cursor, csr);

    {
        int n8 = n * NF / 8;
        k_cvt<<<(n8 + 255) / 256, 256, 0, stream>>>(features, fbf, n8);
        k_cvtw<<<15360 / 256, 256, 0, stream>>>(W1, W3, Wm1, Wm2, W1bf, W3bf, Wm1bf, Wm2bf);
    }

    const int gm128 = (n + 127) / 128;
    const int gm64  = (n + 63) / 64;
    const int nbL   = (n + 3) / 4;   // lap: 4 nodes per 256-thread block

    // ---- conv1 ----
    k_lap<<<nbL, 256, 0, stream>>>(fbf, nullptr, row_off, csr, dinv, 1.f, -1.f, 0.f, bufB, n);
    k_lap<<<nbL, 256, 0, stream>>>(bufB, fbf, row_off, csr, dinv, 2.f, -2.f, -1.f, bufC, n);
    {
        dim3 g(gm128, 2);
        k_gemm_conv<<<g, 256, 0, stream>>>(fbf, bufB, bufC, W1bf, b1,
                                           nullptr, bng, bnb, bnm, bnv, n, 2, bufD);
    }

    // ---- conv2 ----
    k_lap<<<nbL, 256, 0, stream>>>(bufD, nullptr, row_off, csr, dinv, 1.f, -1.f, 0.f, bufB, n);
    k_lap<<<nbL, 256, 0, stream>>>(bufB, bufD, row_off, csr, dinv, 2.f, -2.f, -1.f, bufC, n);
    {
        dim3 g(gm128, 2);
        k_gemm_conv<<<g, 256, 0, stream>>>(bufD, bufB, bufC, W3bf, b3,
                                           bufD, nullptr, nullptr, nullptr, nullptr, n, 3, bufE);
    }

    // ---- fused MLP ----
    k_mlp<<<gm64, 256, 0, stream>>>(bufE, Wm1bf, bm1, Wm2bf, bm2, n, out);
}

// Round 8
// 352.404 us; speedup vs baseline: 1.3014x; 1.2155x over previous
//
#include <hip/hip_runtime.h>
#include <cstdint>
#include <cstddef>

#define NF 128          // feature width (IN_F == HID_F == 128)
#define SCAN_B 256

typedef __attribute__((ext_vector_type(4))) float f32x4;
typedef __attribute__((ext_vector_type(8))) short bf16x8;

static __device__ inline float bf2f(short u) {
    union { unsigned u; float f; } v;
    v.u = ((unsigned)(unsigned short)u) << 16;
    return v.f;
}
static __device__ inline short f2bf(float f) {
    union { float f; unsigned u; } v; v.f = f;
    unsigned r = v.u + 0x7FFF + ((v.u >> 16) & 1);  // RNE
    return (short)(r >> 16);
}
static __device__ inline float u2f(unsigned u) {
    union { unsigned u; float f; } v; v.u = u; return v.f;
}
static __device__ inline unsigned f2u(float f) {
    union { float f; unsigned u; } v; v.f = f; return v.u;
}
static __device__ inline unsigned packbf(float lo, float hi) {
    unsigned ul = f2u(lo), uh = f2u(hi);
    ul = ul + 0x7FFF + ((ul >> 16) & 1);
    uh = uh + 0x7FFF + ((uh >> 16) & 1);
    return (ul >> 16) | (uh & 0xFFFF0000u);
}

// ---------------- degree / CSR build ----------------

static __global__ void k_count(const int* __restrict__ dst, int ne, int* __restrict__ counts) {
    int e = blockIdx.x * blockDim.x + threadIdx.x;
    if (e < ne) atomicAdd(&counts[dst[e]], 1);
}

static __global__ void k_dinv(const int* __restrict__ counts, int n, float* __restrict__ dinv) {
    int i = blockIdx.x * blockDim.x + threadIdx.x;
    if (i < n) {
        float d = (float)counts[i];
        d = fmaxf(d, 1.0f);
        dinv[i] = rsqrtf(d);
    }
}

static __global__ void k_scan1(const int* __restrict__ counts, int n,
                               int* __restrict__ row_off, int* __restrict__ bsum) {
    __shared__ int s[SCAN_B];
    int t = threadIdx.x;
    int base = blockIdx.x * SCAN_B;
    int v = (base + t < n) ? counts[base + t] : 0;
    s[t] = v;
    __syncthreads();
    for (int off = 1; off < SCAN_B; off <<= 1) {
        int x = 0;
        if (t >= off) x = s[t - off];
        __syncthreads();
        if (t >= off) s[t] += x;
        __syncthreads();
    }
    if (base + t < n) row_off[base + t] = s[t] - v;
    if (t == SCAN_B - 1) bsum[blockIdx.x] = s[t];
}

static __global__ void k_scan2(int* __restrict__ bsum, int nb) {
    __shared__ int s[512];
    int t = threadIdx.x;
    int v = (t < nb) ? bsum[t] : 0;
    s[t] = v;
    __syncthreads();
    for (int off = 1; off < 512; off <<= 1) {
        int x = 0;
        if (t >= off) x = s[t - off];
        __syncthreads();
        if (t >= off) s[t] += x;
        __syncthreads();
    }
    if (t < nb) bsum[t] = s[t] - v;
}

static __global__ void k_scan3(int* __restrict__ row_off, const int* __restrict__ bsum,
                               int n, int ne, int* __restrict__ cursor) {
    int i = blockIdx.x * SCAN_B + threadIdx.x;
    if (i < n) {
        int v = row_off[i] + bsum[blockIdx.x];
        row_off[i] = v;
        cursor[i] = v;
    }
    if (i == 0) row_off[n] = ne;
}

static __global__ void k_fill(const int* __restrict__ src, const int* __restrict__ dst, int ne,
                              int* __restrict__ cursor, int* __restrict__ csr) {
    int e = blockIdx.x * blockDim.x + threadIdx.x;
    if (e < ne) {
        int d = dst[e];
        int p = atomicAdd(&cursor[d], 1);
        csr[p] = src[e];
    }
}

// ---------------- fp32 -> bf16 convert ----------------

static __global__ __launch_bounds__(256) void k_cvt(const float* __restrict__ x,
                                                    short* __restrict__ y, int n8) {
    int i = blockIdx.x * blockDim.x + threadIdx.x;
    if (i < n8) {
        f32x4 a = *(const f32x4*)&x[(size_t)i * 8];
        f32x4 b = *(const f32x4*)&x[(size_t)i * 8 + 4];
        bf16x8 r;
        r[0] = f2bf(a[0]); r[1] = f2bf(a[1]); r[2] = f2bf(a[2]); r[3] = f2bf(a[3]);
        r[4] = f2bf(b[0]); r[5] = f2bf(b[1]); r[6] = f2bf(b[2]); r[7] = f2bf(b[3]);
        *(bf16x8*)&y[(size_t)i * 8] = r;
    }
}

// merged weight convert: 4 segments [W1:6144][W3:6144][Wm1:2048][Wm2:1024] x8 chunks
static __global__ __launch_bounds__(256) void k_cvtw(
    const float* __restrict__ w1, const float* __restrict__ w3,
    const float* __restrict__ wm1, const float* __restrict__ wm2,
    short* __restrict__ o1, short* __restrict__ o3,
    short* __restrict__ om1, short* __restrict__ om2) {
    int i = blockIdx.x * blockDim.x + threadIdx.x;   // 0..15359
    const float* x; short* y; int off;
    if (i < 6144)       { x = w1;  y = o1;  off = i; }
    else if (i < 12288) { x = w3;  y = o3;  off = i - 6144; }
    else if (i < 14336) { x = wm1; y = om1; off = i - 12288; }
    else                { x = wm2; y = om2; off = i - 14336; }
    f32x4 a = *(const f32x4*)&x[(size_t)off * 8];
    f32x4 b = *(const f32x4*)&x[(size_t)off * 8 + 4];
    bf16x8 r;
    r[0] = f2bf(a[0]); r[1] = f2bf(a[1]); r[2] = f2bf(a[2]); r[3] = f2bf(a[3]);
    r[4] = f2bf(b[0]); r[5] = f2bf(b[1]); r[6] = f2bf(b[2]); r[7] = f2bf(b[3]);
    *(bf16x8*)&y[(size_t)off * 8] = r;
}

// ---------------- Laplacian gather: one wave per node, 8-edge batched loads ----------------
// out = a*(agg*dinv_i) + b*Xin[i] + c*Xo[i],  agg = sum_src Xin[src]*dinv[src]
// Lanes 0-7 fetch up to 8 edge indices in one go; __shfl broadcasts; all 8 X-row
// loads issue independently (inactive slots -> row 0, L1-hot, weight 0).

static __global__ __launch_bounds__(256) void k_lap(
    const short* __restrict__ Xin, const short* __restrict__ Xo,
    const int* __restrict__ row_off, const int* __restrict__ csr,
    const float* __restrict__ dinv,
    float a, float b, float c,
    short* __restrict__ out, int n) {
    int node = blockIdx.x * 4 + (threadIdx.x >> 6);
    if (node >= n) return;
    int l = threadIdx.x & 63;
    const unsigned* Xu = (const unsigned*)Xin;
    int e0 = row_off[node], e1 = row_off[node + 1];

    float s0 = 0.f, s1 = 0.f;
    for (int base = e0; base < e1; base += 8) {
        int m = e1 - base;              // edges left (>0)
        int idx = 0;
        if (l < 8 && l < m) idx = csr[base + l];
        unsigned v[8]; float dv[8];
#pragma unroll
        for (int j = 0; j < 8; ++j) {
            int src = __shfl(idx, j, 64);
            bool act = (j < m);
            if (!act) src = 0;
            dv[j] = act ? dinv[src] : 0.f;
            v[j] = Xu[(size_t)src * 64 + l];
        }
#pragma unroll
        for (int j = 0; j < 8; ++j) {
            s0 += u2f(v[j] << 16) * dv[j];
            s1 += u2f(v[j] & 0xFFFF0000u) * dv[j];
        }
    }

    float di = dinv[node];
    unsigned xi = Xu[(size_t)node * 64 + l];
    float y0 = a * (s0 * di) + b * u2f(xi << 16);
    float y1 = a * (s1 * di) + b * u2f(xi & 0xFFFF0000u);
    if (Xo) {
        unsigned xo = ((const unsigned*)Xo)[(size_t)node * 64 + l];
        y0 += c * u2f(xo << 16);
        y1 += c * u2f(xo & 0xFFFF0000u);
    }
    ((unsigned*)out)[(size_t)node * 64 + l] = packbf(y0, y1);
}

// ---------------- conv GEMM: out[M][128] = concat(X0,X1,X2)[M][384] @ Wbf[128][384]^T ----
// BM=128, BN=64, BK=32, 4 waves 2x2 (frag 4x2). 1D grid + bijective XCD swizzle so
// both BN-halves of an A-row-block share an XCD (A's 2nd read = L2 hit).
// Depth-2 register prefetch ping-pong + double-buffered LDS, one barrier per K-step:
//   iter t: issue load(t+2) into set[cur]; compute(buf[cur]); write_lds(buf[nxt], set[nxt]); sync.
// mode 2: bn(relu(y+b))   mode 3: relu(y+b)+res.  Output bf16.

#define LDP 40

static __global__ __launch_bounds__(256) void k_gemm_conv(
    const short* __restrict__ X0, const short* __restrict__ X1, const short* __restrict__ X2,
    const short* __restrict__ Wbf, const float* __restrict__ bias,
    const short* __restrict__ res,
    const float* __restrict__ bng, const float* __restrict__ bnb,
    const float* __restrict__ bnm, const float* __restrict__ bnv,
    int M, int mode, short* __restrict__ out) {
    __shared__ short As[2][128 * LDP];
    __shared__ short Bs[2][64 * LDP];

    // bijective XCD swizzle (m204): chunk flat ids per XCD; pairs {2k,2k+1} share bx.
    const int nwg = gridDim.x;
    const int q = nwg >> 3, r = nwg & 7;
    const int xcd = blockIdx.x & 7, slot = blockIdx.x >> 3;
    const int flat = (xcd < r ? xcd * (q + 1) : r * (q + 1) + (xcd - r) * q) + slot;
    const int m0 = (flat >> 1) * 128;
    const int n0 = (flat & 1) * 64;

    const int t = threadIdx.x;
    const int w  = t >> 6;
    const int wr = w >> 1;
    const int wc = w & 1;
    const int l  = t & 63;
    const int lr = l & 15;
    const int lk = l >> 4;

    const short* segs[3] = {X0, X1, X2};

    // A staging: 512 chunks (row 0..127, slot 0..3), 2/thread. B: 256 chunks, 1/thread.
    const int ar0 = t >> 2, as0 = t & 3;
    const int ar1 = (256 + t) >> 2, as1 = t & 3;
    const int br  = t >> 2, bs = t & 3;

    f32x4 acc[4][2];
#pragma unroll
    for (int i = 0; i < 4; ++i)
#pragma unroll
        for (int j = 0; j < 2; ++j) acc[i][j] = (f32x4){0.f, 0.f, 0.f, 0.f};

    bf16x8 ra0[2], ra1[2], rb[2];   // two prefetch sets (static-indexed via full unroll)

    auto load_regs = [&](int set, int kt) {
        const short* Xp = segs[kt >> 7];
        const int klocal = kt & 127;
        int gm0 = m0 + ar0, gm1 = m0 + ar1;
        bf16x8 z = {0, 0, 0, 0, 0, 0, 0, 0};
        ra0[set] = (gm0 < M) ? *(const bf16x8*)&Xp[(size_t)gm0 * 128 + klocal + as0 * 8] : z;
        ra1[set] = (gm1 < M) ? *(const bf16x8*)&Xp[(size_t)gm1 * 128 + klocal + as1 * 8] : z;
        rb[set]  = *(const bf16x8*)&Wbf[(size_t)(n0 + br) * 384 + kt + bs * 8];
    };
    auto write_lds = [&](int buf, int set) {
        *(bf16x8*)&As[buf][ar0 * LDP + as0 * 8] = ra0[set];
        *(bf16x8*)&As[buf][ar1 * LDP + as1 * 8] = ra1[set];
        *(bf16x8*)&Bs[buf][br * LDP + bs * 8] = rb[set];
    };
    auto compute = [&](int buf) {
        bf16x8 af[4], bfr[2];
#pragma unroll
        for (int fi = 0; fi < 4; ++fi)
            af[fi] = *(const bf16x8*)&As[buf][(wr * 64 + fi * 16 + lr) * LDP + lk * 8];
#pragma unroll
        for (int fj = 0; fj < 2; ++fj)
            bfr[fj] = *(const bf16x8*)&Bs[buf][(wc * 32 + fj * 16 + lr) * LDP + lk * 8];
#pragma unroll
        for (int fi = 0; fi < 4; ++fi)
#pragma unroll
            for (int fj = 0; fj < 2; ++fj)
                acc[fi][fj] = __builtin_amdgcn_mfma_f32_16x16x32_bf16(af[fi], bfr[fj], acc[fi][fj], 0, 0, 0);
    };

    load_regs(0, 0);
    write_lds(0, 0);
    load_regs(1, 32);          // tile 1 in flight
    __syncthreads();
#pragma unroll
    for (int tgt = 0; tgt < 12; ++tgt) {
        const int cur = tgt & 1, nxt = (tgt + 1) & 1;
        if (tgt < 10) load_regs(cur, (tgt + 2) * 32);  // set[cur] free: tile tgt already in LDS
        compute(cur);
        if (tgt < 11) {
            write_lds(nxt, nxt);                       // tile tgt+1 -> other LDS buffer
            __syncthreads();
        }
    }

    // epilogue: C row = lk*4+reg, col = lr
#pragma unroll
    for (int fi = 0; fi < 4; ++fi) {
#pragma unroll
        for (int reg = 0; reg < 4; ++reg) {
            int gm = m0 + wr * 64 + fi * 16 + lk * 4 + reg;
            if (gm >= M) continue;
#pragma unroll
            for (int fj = 0; fj < 2; ++fj) {
                int gn = n0 + wc * 32 + fj * 16 + lr;
                float y = acc[fi][fj][reg] + bias[gn];
                y = fmaxf(y, 0.f);
                if (mode == 2) {
                    float sc = rsqrtf(bnv[gn] + 1e-5f) * bng[gn];
                    y = (y - bnm[gn]) * sc + bnb[gn];
                } else {
                    y += bf2f(res[(size_t)gm * 128 + gn]);
                }
                out[(size_t)gm * 128 + gn] = f2bf(y);
            }
        }
    }
}

// ---------------- fused MLP: out[M][64] = relu(x@Wm1^T+bm1) @ Wm2^T + bm2 ----------------

static __global__ __launch_bounds__(256) void k_mlp(
    const short* __restrict__ X, const short* __restrict__ Wm1bf, const float* __restrict__ bm1,
    const short* __restrict__ Wm2bf, const float* __restrict__ bm2,
    int M, float* __restrict__ out) {
    __shared__ short As[64 * LDP];       // phase1 A tile / phase2 B tile
    __shared__ short Bs[128 * LDP];      // phase1 Wm1 tile
    __shared__ short hs[64 * 136];       // h, padded stride 136

    const int t = threadIdx.x;
    const int m0 = blockIdx.x * 64;
    const int w  = t >> 6;
    const int wr = w >> 1;
    const int wc = w & 1;
    const int l  = t & 63;
    const int lr = l & 15;
    const int lk = l >> 4;

    f32x4 acc1[2][4];
#pragma unroll
    for (int i = 0; i < 2; ++i)
#pragma unroll
        for (int j = 0; j < 4; ++j) acc1[i][j] = (f32x4){0.f, 0.f, 0.f, 0.f};

    for (int kt = 0; kt < 128; kt += 32) {
        {
            int row = t >> 2;
            int slot = t & 3;
            int gm = m0 + row;
            bf16x8 v = {0, 0, 0, 0, 0, 0, 0, 0};
            if (gm < M) v = *(const bf16x8*)&X[(size_t)gm * 128 + kt + slot * 8];
            *(bf16x8*)&As[row * LDP + slot * 8] = v;
        }
#pragma unroll
        for (int it = 0; it < 2; ++it) {
            int idx = it * 256 + t;
            int row = idx >> 2;
            int slot = idx & 3;
            bf16x8 v = *(const bf16x8*)&Wm1bf[(size_t)row * 128 + kt + slot * 8];
            *(bf16x8*)&Bs[row * LDP + slot * 8] = v;
        }
        __syncthreads();

        bf16x8 af[2], bfr[4];
#pragma unroll
        for (int fi = 0; fi < 2; ++fi)
            af[fi] = *(const bf16x8*)&As[(wr * 32 + fi * 16 + lr) * LDP + lk * 8];
#pragma unroll
        for (int fj = 0; fj < 4; ++fj)
            bfr[fj] = *(const bf16x8*)&Bs[(wc * 64 + fj * 16 + lr) * LDP + lk * 8];
#pragma unroll
        for (int fi = 0; fi < 2; ++fi)
#pragma unroll
            for (int fj = 0; fj < 4; ++fj)
                acc1[fi][fj] = __builtin_amdgcn_mfma_f32_16x16x32_bf16(af[fi], bfr[fj], acc1[fi][fj], 0, 0, 0);
        __syncthreads();
    }

#pragma unroll
    for (int fi = 0; fi < 2; ++fi) {
#pragma unroll
        for (int reg = 0; reg < 4; ++reg) {
            int rloc = wr * 32 + fi * 16 + lk * 4 + reg;
#pragma unroll
            for (int fj = 0; fj < 4; ++fj) {
                int col = wc * 64 + fj * 16 + lr;
                float y = acc1[fi][fj][reg] + bm1[col];
                hs[rloc * 136 + col] = f2bf(fmaxf(y, 0.f));
            }
        }
    }
    __syncthreads();

    f32x4 acc2[2][2];
#pragma unroll
    for (int i = 0; i < 2; ++i)
#pragma unroll
        for (int j = 0; j < 2; ++j) acc2[i][j] = (f32x4){0.f, 0.f, 0.f, 0.f};

    for (int kt = 0; kt < 128; kt += 32) {
        {
            int row = t >> 2;
            int slot = t & 3;
            bf16x8 v = *(const bf16x8*)&Wm2bf[(size_t)row * 128 + kt + slot * 8];
            *(bf16x8*)&As[row * LDP + slot * 8] = v;
        }
        __syncthreads();

        bf16x8 af[2], bfr[2];
#pragma unroll
        for (int fi = 0; fi < 2; ++fi)
            af[fi] = *(const bf16x8*)&hs[(wr * 32 + fi * 16 + lr) * 136 + kt + lk * 8];
#pragma unroll
        for (int fj = 0; fj < 2; ++fj)
            bfr[fj] = *(const bf16x8*)&As[(wc * 32 + fj * 16 + lr) * LDP + lk * 8];
#pragma unroll
        for (int fi = 0; fi < 2; ++fi)
#pragma unroll
            for (int fj = 0; fj < 2; ++fj)
                acc2[fi][fj] = __builtin_amdgcn_mfma_f32_16x16x32_bf16(af[fi], bfr[fj], acc2[fi][fj], 0, 0, 0);
        __syncthreads();
    }

#pragma unroll
    for (int fi = 0; fi < 2; ++fi) {
#pragma unroll
        for (int reg = 0; reg < 4; ++reg) {
            int gm = m0 + wr * 32 + fi * 16 + lk * 4 + reg;
            if (gm >= M) continue;
#pragma unroll
            for (int fj = 0; fj < 2; ++fj) {
                int gn = wc * 32 + fj * 16 + lr;
                out[(size_t)gm * 64 + gn] = acc2[fi][fj][reg] + bm2[gn];
            }
        }
    }
}

// ---------------- launch ----------------

extern "C" void kernel_launch(void* const* d_in, const int* in_sizes, int n_in,
                              void* d_out, int out_size, void* d_ws, size_t ws_size,
                              hipStream_t stream) {
    const float* features = (const float*)d_in[0];
    const int*   esrc     = (const int*)d_in[1];
    const int*   edst     = (const int*)d_in[2];
    const float* W1   = (const float*)d_in[3];
    const float* b1   = (const float*)d_in[4];
    const float* bng  = (const float*)d_in[5];
    const float* bnb  = (const float*)d_in[6];
    const float* bnm  = (const float*)d_in[7];
    const float* bnv  = (const float*)d_in[8];
    const float* W3   = (const float*)d_in[9];
    const float* b3   = (const float*)d_in[10];
    const float* Wm1  = (const float*)d_in[11];
    const float* bm1  = (const float*)d_in[12];
    const float* Wm2  = (const float*)d_in[13];
    const float* bm2  = (const float*)d_in[14];
    float* out = (float*)d_out;

    const int n  = in_sizes[0] / NF;     // 100000
    const int ne = in_sizes[1];          // 600000

    uint8_t* w = (uint8_t*)d_ws;
    size_t off = 0;
    auto alloc = [&](size_t bytes) -> void* {
        void* p = w + off;
        off = (off + bytes + 255) & ~(size_t)255;
        return p;
    };
    float* dinv   = (float*)alloc((size_t)n * 4);
    int* counts   = (int*)alloc((size_t)n * 4);
    int* row_off  = (int*)alloc(((size_t)n + 1) * 4);
    int* cursor   = (int*)alloc((size_t)n * 4);
    int* csr      = (int*)alloc((size_t)ne * 4);
    int* bsum     = (int*)alloc(4096);
    short* fbf    = (short*)alloc((size_t)n * NF * 2);
    short* bufB   = (short*)alloc((size_t)n * NF * 2);
    short* bufC   = (short*)alloc((size_t)n * NF * 2);
    short* bufD   = (short*)alloc((size_t)n * NF * 2);
    short* bufE   = (short*)alloc((size_t)n * NF * 2);
    short* W1bf   = (short*)alloc((size_t)128 * 384 * 2);
    short* W3bf   = (short*)alloc((size_t)128 * 384 * 2);
    short* Wm1bf  = (short*)alloc((size_t)128 * 128 * 2);
    short* Wm2bf  = (short*)alloc((size_t)64 * 128 * 2);
    (void)ws_size;

    const int TB = 256;
    const int nbE = (ne + TB - 1) / TB;
    const int nbN = (n + TB - 1) / TB;

    hipMemsetAsync(counts, 0, (size_t)n * 4, stream);
    k_count<<<nbE, TB, 0, stream>>>(edst, ne, counts);
    k_dinv<<<nbN, TB, 0, stream>>>(counts, n, dinv);
    k_scan1<<<nbN, SCAN_B, 0, stream>>>(counts, n, row_off, bsum);
    k_scan2<<<1, 512, 0, stream>>>(bsum, nbN);
    k_scan3<<<nbN, SCAN_B, 0, stream>>>(row_off, bsum, n, ne, cursor);
    k_fill<<<nbE, TB, 0, stream>>>(esrc, edst, ne, cursor, csr);

    {
        int n8 = n * NF / 8;
        k_cvt<<<(n8 + 255) / 256, 256, 0, stream>>>(features, fbf, n8);
        k_cvtw<<<15360 / 256, 256, 0, stream>>>(W1, W3, Wm1, Wm2, W1bf, W3bf, Wm1bf, Wm2bf);
    }

    const int gm128 = (n + 127) / 128;
    const int gm64  = (n + 63) / 64;
    const int nbL   = (n + 3) / 4;   // lap: 4 nodes per 256-thread block
    const int nwg   = gm128 * 2;     // conv GEMM 1D grid (XCD-swizzled inside)

    // ---- conv1 ----
    k_lap<<<nbL, 256, 0, stream>>>(fbf, nullptr, row_off, csr, dinv, 1.f, -1.f, 0.f, bufB, n);
    k_lap<<<nbL, 256, 0, stream>>>(bufB, fbf, row_off, csr, dinv, 2.f, -2.f, -1.f, bufC, n);
    k_gemm_conv<<<nwg, 256, 0, stream>>>(fbf, bufB, bufC, W1bf, b1,
                                         nullptr, bng, bnb, bnm, bnv, n, 2, bufD);

    // ---- conv2 ----
    k_lap<<<nbL, 256, 0, stream>>>(bufD, nullptr, row_off, csr, dinv, 1.f, -1.f, 0.f, bufB, n);
    k_lap<<<nbL, 256, 0, stream>>>(bufB, bufD, row_off, csr, dinv, 2.f, -2.f, -1.f, bufC, n);
    k_gemm_conv<<<nwg, 256, 0, stream>>>(bufD, bufB, bufC, W3bf, b3,
                                         bufD, nullptr, nullptr, nullptr, nullptr, n, 3, bufE);

    // ---- fused MLP ----
    k_mlp<<<gm64, 256, 0, stream>>>(bufE, Wm1bf, bm1, Wm2bf, bm2, n, out);
}

// Round 9
// 346.819 us; speedup vs baseline: 1.3223x; 1.0161x over previous
//
#include <hip/hip_runtime.h>
#include <cstdint>
#include <cstddef>

#define NF 128          // feature width (IN_F == HID_F == 128)
#define SCAN_B 256

typedef __attribute__((ext_vector_type(4))) float f32x4;
typedef __attribute__((ext_vector_type(8))) short bf16x8;

#define GL2LDS16(g, l) __builtin_amdgcn_global_load_lds(                     \
    (const __attribute__((address_space(1))) unsigned*)(g),                  \
    (__attribute__((address_space(3))) unsigned*)(l), 16, 0, 0)

static __device__ inline float bf2f(short u) {
    union { unsigned u; float f; } v;
    v.u = ((unsigned)(unsigned short)u) << 16;
    return v.f;
}
static __device__ inline short f2bf(float f) {
    union { float f; unsigned u; } v; v.f = f;
    unsigned r = v.u + 0x7FFF + ((v.u >> 16) & 1);  // RNE
    return (short)(r >> 16);
}
static __device__ inline float u2f(unsigned u) {
    union { unsigned u; float f; } v; v.u = u; return v.f;
}
static __device__ inline unsigned f2u(float f) {
    union { float f; unsigned u; } v; v.f = f; return v.u;
}
static __device__ inline unsigned packbf(float lo, float hi) {
    unsigned ul = f2u(lo), uh = f2u(hi);
    ul = ul + 0x7FFF + ((ul >> 16) & 1);
    uh = uh + 0x7FFF + ((uh >> 16) & 1);
    return (ul >> 16) | (uh & 0xFFFF0000u);
}

// ---------------- degree / CSR build ----------------

static __global__ void k_count(const int* __restrict__ dst, int ne, int* __restrict__ counts) {
    int e = blockIdx.x * blockDim.x + threadIdx.x;
    if (e < ne) atomicAdd(&counts[dst[e]], 1);
}

static __global__ void k_scan1(const int* __restrict__ counts, int n,
                               int* __restrict__ row_off, int* __restrict__ bsum) {
    __shared__ int s[SCAN_B];
    int t = threadIdx.x;
    int base = blockIdx.x * SCAN_B;
    int v = (base + t < n) ? counts[base + t] : 0;
    s[t] = v;
    __syncthreads();
    for (int off = 1; off < SCAN_B; off <<= 1) {
        int x = 0;
        if (t >= off) x = s[t - off];
        __syncthreads();
        if (t >= off) s[t] += x;
        __syncthreads();
    }
    if (base + t < n) row_off[base + t] = s[t] - v;
    if (t == SCAN_B - 1) bsum[blockIdx.x] = s[t];
}

static __global__ void k_scan2(int* __restrict__ bsum, int nb) {
    __shared__ int s[512];
    int t = threadIdx.x;
    int v = (t < nb) ? bsum[t] : 0;
    s[t] = v;
    __syncthreads();
    for (int off = 1; off < 512; off <<= 1) {
        int x = 0;
        if (t >= off) x = s[t - off];
        __syncthreads();
        if (t >= off) s[t] += x;
        __syncthreads();
    }
    if (t < nb) bsum[t] = s[t] - v;
}

// scan3 + dinv fused
static __global__ void k_scan3(int* __restrict__ row_off, const int* __restrict__ bsum,
                               int n, int ne, int* __restrict__ cursor,
                               const int* __restrict__ counts, float* __restrict__ dinv) {
    int i = blockIdx.x * SCAN_B + threadIdx.x;
    if (i < n) {
        int v = row_off[i] + bsum[blockIdx.x];
        row_off[i] = v;
        cursor[i] = v;
        float d = fmaxf((float)counts[i], 1.0f);
        dinv[i] = rsqrtf(d);
    }
    if (i == 0) row_off[n] = ne;
}

static __global__ void k_fill(const int* __restrict__ src, const int* __restrict__ dst, int ne,
                              int* __restrict__ cursor, int* __restrict__ csr) {
    int e = blockIdx.x * blockDim.x + threadIdx.x;
    if (e < ne) {
        int d = dst[e];
        int p = atomicAdd(&cursor[d], 1);
        csr[p] = src[e];
    }
}

// ---------------- fp32 -> bf16 convert ----------------

static __global__ __launch_bounds__(256) void k_cvt(const float* __restrict__ x,
                                                    short* __restrict__ y, int n8) {
    int i = blockIdx.x * blockDim.x + threadIdx.x;
    if (i < n8) {
        f32x4 a = *(const f32x4*)&x[(size_t)i * 8];
        f32x4 b = *(const f32x4*)&x[(size_t)i * 8 + 4];
        bf16x8 r;
        r[0] = f2bf(a[0]); r[1] = f2bf(a[1]); r[2] = f2bf(a[2]); r[3] = f2bf(a[3]);
        r[4] = f2bf(b[0]); r[5] = f2bf(b[1]); r[6] = f2bf(b[2]); r[7] = f2bf(b[3]);
        *(bf16x8*)&y[(size_t)i * 8] = r;
    }
}

// merged weight convert: 4 segments [W1:6144][W3:6144][Wm1:2048][Wm2:1024] x8 chunks
static __global__ __launch_bounds__(256) void k_cvtw(
    const float* __restrict__ w1, const float* __restrict__ w3,
    const float* __restrict__ wm1, const float* __restrict__ wm2,
    short* __restrict__ o1, short* __restrict__ o3,
    short* __restrict__ om1, short* __restrict__ om2) {
    int i = blockIdx.x * blockDim.x + threadIdx.x;   // 0..15359
    const float* x; short* y; int off;
    if (i < 6144)       { x = w1;  y = o1;  off = i; }
    else if (i < 12288) { x = w3;  y = o3;  off = i - 6144; }
    else if (i < 14336) { x = wm1; y = om1; off = i - 12288; }
    else                { x = wm2; y = om2; off = i - 14336; }
    f32x4 a = *(const f32x4*)&x[(size_t)off * 8];
    f32x4 b = *(const f32x4*)&x[(size_t)off * 8 + 4];
    bf16x8 r;
    r[0] = f2bf(a[0]); r[1] = f2bf(a[1]); r[2] = f2bf(a[2]); r[3] = f2bf(a[3]);
    r[4] = f2bf(b[0]); r[5] = f2bf(b[1]); r[6] = f2bf(b[2]); r[7] = f2bf(b[3]);
    *(bf16x8*)&y[(size_t)off * 8] = r;
}

// ---------------- Laplacian gather: one wave per node, 8-edge batched loads ----------------

static __global__ __launch_bounds__(256) void k_lap(
    const short* __restrict__ Xin, const short* __restrict__ Xo,
    const int* __restrict__ row_off, const int* __restrict__ csr,
    const float* __restrict__ dinv,
    float a, float b, float c,
    short* __restrict__ out, int n) {
    int node = blockIdx.x * 4 + (threadIdx.x >> 6);
    if (node >= n) return;
    int l = threadIdx.x & 63;
    const unsigned* Xu = (const unsigned*)Xin;
    int e0 = row_off[node], e1 = row_off[node + 1];

    float s0 = 0.f, s1 = 0.f;
    for (int base = e0; base < e1; base += 8) {
        int m = e1 - base;              // edges left (>0)
        int idx = 0;
        if (l < 8 && l < m) idx = csr[base + l];
        unsigned v[8]; float dv[8];
#pragma unroll
        for (int j = 0; j < 8; ++j) {
            int src = __shfl(idx, j, 64);
            bool act = (j < m);
            if (!act) src = 0;
            dv[j] = act ? dinv[src] : 0.f;
            v[j] = Xu[(size_t)src * 64 + l];
        }
#pragma unroll
        for (int j = 0; j < 8; ++j) {
            s0 += u2f(v[j] << 16) * dv[j];
            s1 += u2f(v[j] & 0xFFFF0000u) * dv[j];
        }
    }

    float di = dinv[node];
    unsigned xi = Xu[(size_t)node * 64 + l];
    float y0 = a * (s0 * di) + b * u2f(xi << 16);
    float y1 = a * (s1 * di) + b * u2f(xi & 0xFFFF0000u);
    if (Xo) {
        unsigned xo = ((const unsigned*)Xo)[(size_t)node * 64 + l];
        y0 += c * u2f(xo << 16);
        y1 += c * u2f(xo & 0xFFFF0000u);
    }
    ((unsigned*)out)[(size_t)node * 64 + l] = packbf(y0, y1);
}

// ---------------- conv GEMM: out[M][128] = concat(X0,X1,X2)[M][384] @ Wbf[128][384]^T ----
// BM=128, BN=64, BK=32, 4 waves 2x2 (frag 4x2). 1D grid + bijective XCD swizzle.
// Staging via global_load_lds (16B/lane, wave-uniform LDS base), double-buffered,
// ONE barrier per K-step:  issue(buf^1, t+1) -> compute(buf) -> barrier.
// LDS is linear [row][32]; bank conflicts broken by XOR-ing the 16B slot with
// (row>>1)&3 on BOTH the global source address and the ds_read (rule #21).
// mode 2: bn(relu(y+b))   mode 3: relu(y+b)+res.  Output bf16.

static __global__ __launch_bounds__(256) void k_gemm_conv(
    const short* __restrict__ X0, const short* __restrict__ X1, const short* __restrict__ X2,
    const short* __restrict__ Wbf, const float* __restrict__ bias,
    const short* __restrict__ res,
    const float* __restrict__ bng, const float* __restrict__ bnb,
    const float* __restrict__ bnm, const float* __restrict__ bnv,
    int M, int mode, short* __restrict__ out) {
    __shared__ short As[2][128 * 32];
    __shared__ short Bs[2][64 * 32];

    // bijective XCD swizzle (m204); pairs {2k,2k+1} share the A row-block.
    const int nwg = gridDim.x;
    const int q = nwg >> 3, r = nwg & 7;
    const int xcd = blockIdx.x & 7, slot = blockIdx.x >> 3;
    const int flat = (xcd < r ? xcd * (q + 1) : r * (q + 1) + (xcd - r) * q) + slot;
    const int m0 = (flat >> 1) * 128;
    const int n0 = (flat & 1) * 64;

    const int t = threadIdx.x;
    const int wv = t >> 6;
    const int ln = t & 63;
    const int wr = wv >> 1;
    const int wc = wv & 1;
    const int lr = ln & 15;
    const int lk = ln >> 4;

    const short* segs[3] = {X0, X1, X2};

    // chunk geometry: A tile = 512 chunks of 16B (row=c>>2, slot=c&3); B = 256 chunks.
    f32x4 acc[4][2];
#pragma unroll
    for (int i = 0; i < 4; ++i)
#pragma unroll
        for (int j = 0; j < 2; ++j) acc[i][j] = (f32x4){0.f, 0.f, 0.f, 0.f};

    auto issue = [&](int buf, int kt) {
        const short* Xp = segs[kt >> 7];
        const int klocal = kt & 127;
#pragma unroll
        for (int j = 0; j < 2; ++j) {
            int c = (wv * 2 + j) * 64 + ln;
            int row = c >> 2, sl = c & 3;
            int gm = m0 + row;
            if (gm > M - 1) gm = M - 1;            // clamp: valid addr, row unused in epilogue
            const short* g = &Xp[(size_t)gm * 128 + klocal + ((sl ^ ((row >> 1) & 3)) * 8)];
            GL2LDS16(g, &As[buf][(wv * 2 + j) * 512]);   // 64 lanes x 16B = 1KB linear
        }
        {
            int c = wv * 64 + ln;
            int row = c >> 2, sl = c & 3;
            const short* g = &Wbf[(size_t)(n0 + row) * 384 + kt + ((sl ^ ((row >> 1) & 3)) * 8)];
            GL2LDS16(g, &Bs[buf][wv * 512]);
        }
    };
    auto compute = [&](int buf) {
        bf16x8 af[4], bfr[2];
#pragma unroll
        for (int fi = 0; fi < 4; ++fi) {
            int row = wr * 64 + fi * 16 + lr;
            af[fi] = *(const bf16x8*)&As[buf][row * 32 + ((lk ^ ((row >> 1) & 3)) * 8)];
        }
#pragma unroll
        for (int fj = 0; fj < 2; ++fj) {
            int row = wc * 32 + fj * 16 + lr;
            bfr[fj] = *(const bf16x8*)&Bs[buf][row * 32 + ((lk ^ ((row >> 1) & 3)) * 8)];
        }
#pragma unroll
        for (int fi = 0; fi < 4; ++fi)
#pragma unroll
            for (int fj = 0; fj < 2; ++fj)
                acc[fi][fj] = __builtin_amdgcn_mfma_f32_16x16x32_bf16(af[fi], bfr[fj], acc[fi][fj], 0, 0, 0);
    };

    issue(0, 0);
    __syncthreads();                       // vmcnt drained by compiler before barrier
#pragma unroll
    for (int tgt = 0; tgt < 12; ++tgt) {
        if (tgt < 11) issue((tgt + 1) & 1, (tgt + 1) * 32);  // async DMA into other buffer
        compute(tgt & 1);                                     // hides the DMA
        __syncthreads();                                      // reads done + loads landed
    }

    // epilogue: C row = lk*4+reg, col = lr
#pragma unroll
    for (int fi = 0; fi < 4; ++fi) {
#pragma unroll
        for (int reg = 0; reg < 4; ++reg) {
            int gm = m0 + wr * 64 + fi * 16 + lk * 4 + reg;
            if (gm >= M) continue;
#pragma unroll
            for (int fj = 0; fj < 2; ++fj) {
                int gn = n0 + wc * 32 + fj * 16 + lr;
                float y = acc[fi][fj][reg] + bias[gn];
                y = fmaxf(y, 0.f);
                if (mode == 2) {
                    float sc = rsqrtf(bnv[gn] + 1e-5f) * bng[gn];
                    y = (y - bnm[gn]) * sc + bnb[gn];
                } else {
                    y += bf2f(res[(size_t)gm * 128 + gn]);
                }
                out[(size_t)gm * 128 + gn] = f2bf(y);
            }
        }
    }
}

// ---------------- fused MLP: out[M][64] = relu(x@Wm1^T+bm1) @ Wm2^T + bm2 ----------------

#define LDP 40

static __global__ __launch_bounds__(256) void k_mlp(
    const short* __restrict__ X, const short* __restrict__ Wm1bf, const float* __restrict__ bm1,
    const short* __restrict__ Wm2bf, const float* __restrict__ bm2,
    int M, float* __restrict__ out) {
    __shared__ short As[64 * LDP];       // phase1 A tile / phase2 B tile
    __shared__ short Bs[128 * LDP];      // phase1 Wm1 tile
    __shared__ short hs[64 * 136];       // h, padded stride 136

    const int t = threadIdx.x;
    const int m0 = blockIdx.x * 64;
    const int w  = t >> 6;
    const int wr = w >> 1;
    const int wc = w & 1;
    const int l  = t & 63;
    const int lr = l & 15;
    const int lk = l >> 4;

    f32x4 acc1[2][4];
#pragma unroll
    for (int i = 0; i < 2; ++i)
#pragma unroll
        for (int j = 0; j < 4; ++j) acc1[i][j] = (f32x4){0.f, 0.f, 0.f, 0.f};

    for (int kt = 0; kt < 128; kt += 32) {
        {
            int row = t >> 2;
            int slot = t & 3;
            int gm = m0 + row;
            bf16x8 v = {0, 0, 0, 0, 0, 0, 0, 0};
            if (gm < M) v = *(const bf16x8*)&X[(size_t)gm * 128 + kt + slot * 8];
            *(bf16x8*)&As[row * LDP + slot * 8] = v;
        }
#pragma unroll
        for (int it = 0; it < 2; ++it) {
            int idx = it * 256 + t;
            int row = idx >> 2;
            int slot = idx & 3;
            bf16x8 v = *(const bf16x8*)&Wm1bf[(size_t)row * 128 + kt + slot * 8];
            *(bf16x8*)&Bs[row * LDP + slot * 8] = v;
        }
        __syncthreads();

        bf16x8 af[2], bfr[4];
#pragma unroll
        for (int fi = 0; fi < 2; ++fi)
            af[fi] = *(const bf16x8*)&As[(wr * 32 + fi * 16 + lr) * LDP + lk * 8];
#pragma unroll
        for (int fj = 0; fj < 4; ++fj)
            bfr[fj] = *(const bf16x8*)&Bs[(wc * 64 + fj * 16 + lr) * LDP + lk * 8];
#pragma unroll
        for (int fi = 0; fi < 2; ++fi)
#pragma unroll
            for (int fj = 0; fj < 4; ++fj)
                acc1[fi][fj] = __builtin_amdgcn_mfma_f32_16x16x32_bf16(af[fi], bfr[fj], acc1[fi][fj], 0, 0, 0);
        __syncthreads();
    }

#pragma unroll
    for (int fi = 0; fi < 2; ++fi) {
#pragma unroll
        for (int reg = 0; reg < 4; ++reg) {
            int rloc = wr * 32 + fi * 16 + lk * 4 + reg;
#pragma unroll
            for (int fj = 0; fj < 4; ++fj) {
                int col = wc * 64 + fj * 16 + lr;
                float y = acc1[fi][fj][reg] + bm1[col];
                hs[rloc * 136 + col] = f2bf(fmaxf(y, 0.f));
            }
        }
    }
    __syncthreads();

    f32x4 acc2[2][2];
#pragma unroll
    for (int i = 0; i < 2; ++i)
#pragma unroll
        for (int j = 0; j < 2; ++j) acc2[i][j] = (f32x4){0.f, 0.f, 0.f, 0.f};

    for (int kt = 0; kt < 128; kt += 32) {
        {
            int row = t >> 2;
            int slot = t & 3;
            bf16x8 v = *(const bf16x8*)&Wm2bf[(size_t)row * 128 + kt + slot * 8];
            *(bf16x8*)&As[row * LDP + slot * 8] = v;
        }
        __syncthreads();

        bf16x8 af[2], bfr[2];
#pragma unroll
        for (int fi = 0; fi < 2; ++fi)
            af[fi] = *(const bf16x8*)&hs[(wr * 32 + fi * 16 + lr) * 136 + kt + lk * 8];
#pragma unroll
        for (int fj = 0; fj < 2; ++fj)
            bfr[fj] = *(const bf16x8*)&As[(wc * 32 + fj * 16 + lr) * LDP + lk * 8];
#pragma unroll
        for (int fi = 0; fi < 2; ++fi)
#pragma unroll
            for (int fj = 0; fj < 2; ++fj)
                acc2[fi][fj] = __builtin_amdgcn_mfma_f32_16x16x32_bf16(af[fi], bfr[fj], acc2[fi][fj], 0, 0, 0);
        __syncthreads();
    }

#pragma unroll
    for (int fi = 0; fi < 2; ++fi) {
#pragma unroll
        for (int reg = 0; reg < 4; ++reg) {
            int gm = m0 + wr * 32 + fi * 16 + lk * 4 + reg;
            if (gm >= M) continue;
#pragma unroll
            for (int fj = 0; fj < 2; ++fj) {
                int gn = wc * 32 + fj * 16 + lr;
                out[(size_t)gm * 64 + gn] = acc2[fi][fj][reg] + bm2[gn];
            }
        }
    }
}

// ---------------- launch ----------------

extern "C" void kernel_launch(void* const* d_in, const int* in_sizes, int n_in,
                              void* d_out, int out_size, void* d_ws, size_t ws_size,
                              hipStream_t stream) {
    const float* features = (const float*)d_in[0];
    const int*   esrc     = (const int*)d_in[1];
    const int*   edst     = (const int*)d_in[2];
    const float* W1   = (const float*)d_in[3];
    const float* b1   = (const float*)d_in[4];
    const float* bng  = (const float*)d_in[5];
    const float* bnb  = (const float*)d_in[6];
    const float* bnm  = (const float*)d_in[7];
    const float* bnv  = (const float*)d_in[8];
    const float* W3   = (const float*)d_in[9];
    const float* b3   = (const float*)d_in[10];
    const float* Wm1  = (const float*)d_in[11];
    const float* bm1  = (const float*)d_in[12];
    const float* Wm2  = (const float*)d_in[13];
    const float* bm2  = (const float*)d_in[14];
    float* out = (float*)d_out;

    const int n  = in_sizes[0] / NF;     // 100000
    const int ne = in_sizes[1];          // 600000

    uint8_t* w = (uint8_t*)d_ws;
    size_t off = 0;
    auto alloc = [&](size_t bytes) -> void* {
        void* p = w + off;
        off = (off + bytes + 255) & ~(size_t)255;
        return p;
    };
    float* dinv   = (float*)alloc((size_t)n * 4);
    int* counts   = (int*)alloc((size_t)n * 4);
    int* row_off  = (int*)alloc(((size_t)n + 1) * 4);
    int* cursor   = (int*)alloc((size_t)n * 4);
    int* csr      = (int*)alloc((size_t)ne * 4);
    int* bsum     = (int*)alloc(4096);
    short* fbf    = (short*)alloc((size_t)n * NF * 2);
    short* bufB   = (short*)alloc((size_t)n * NF * 2);
    short* bufC   = (short*)alloc((size_t)n * NF * 2);
    short* bufD   = (short*)alloc((size_t)n * NF * 2);
    short* bufE   = (short*)alloc((size_t)n * NF * 2);
    short* W1bf   = (short*)alloc((size_t)128 * 384 * 2);
    short* W3bf   = (short*)alloc((size_t)128 * 384 * 2);
    short* Wm1bf  = (short*)alloc((size_t)128 * 128 * 2);
    short* Wm2bf  = (short*)alloc((size_t)64 * 128 * 2);
    (void)ws_size;

    const int TB = 256;
    const int nbE = (ne + TB - 1) / TB;
    const int nbN = (n + TB - 1) / TB;

    hipMemsetAsync(counts, 0, (size_t)n * 4, stream);
    k_count<<<nbE, TB, 0, stream>>>(edst, ne, counts);
    k_scan1<<<nbN, SCAN_B, 0, stream>>>(counts, n, row_off, bsum);
    k_scan2<<<1, 512, 0, stream>>>(bsum, nbN);
    k_scan3<<<nbN, SCAN_B, 0, stream>>>(row_off, bsum, n, ne, cursor, counts, dinv);
    k_fill<<<nbE, TB, 0, stream>>>(esrc, edst, ne, cursor, csr);

    {
        int n8 = n * NF / 8;
        k_cvt<<<(n8 + 255) / 256, 256, 0, stream>>>(features, fbf, n8);
        k_cvtw<<<15360 / 256, 256, 0, stream>>>(W1, W3, Wm1, Wm2, W1bf, W3bf, Wm1bf, Wm2bf);
    }

    const int gm128 = (n + 127) / 128;
    const int gm64  = (n + 63) / 64;
    const int nbL   = (n + 3) / 4;   // lap: 4 nodes per 256-thread block
    const int nwg   = gm128 * 2;     // conv GEMM 1D grid (XCD-swizzled inside)

    // ---- conv1 ----
    k_lap<<<nbL, 256, 0, stream>>>(fbf, nullptr, row_off, csr, dinv, 1.f, -1.f, 0.f, bufB, n);
    k_lap<<<nbL, 256, 0, stream>>>(bufB, fbf, row_off, csr, dinv, 2.f, -2.f, -1.f, bufC, n);
    k_gemm_conv<<<nwg, 256, 0, stream>>>(fbf, bufB, bufC, W1bf, b1,
                                         nullptr, bng, bnb, bnm, bnv, n, 2, bufD);

    // ---- conv2 ----
    k_lap<<<nbL, 256, 0, stream>>>(bufD, nullptr, row_off, csr, dinv, 1.f, -1.f, 0.f, bufB, n);
    k_lap<<<nbL, 256, 0, stream>>>(bufB, bufD, row_off, csr, dinv, 2.f, -2.f, -1.f, bufC, n);
    k_gemm_conv<<<nwg, 256, 0, stream>>>(bufD, bufB, bufC, W3bf, b3,
                                         bufD, nullptr, nullptr, nullptr, nullptr, n, 3, bufE);

    // ---- fused MLP ----
    k_mlp<<<gm64, 256, 0, stream>>>(bufE, Wm1bf, bm1, Wm2bf, bm2, n, out);
}